// Round 12
// baseline (258.133 us; speedup 1.0000x reference)
//
#include <hip/hip_runtime.h>
#include <hip/hip_bf16.h>

#define N_NODES 100000
#define N_EDGES 600000
#define N_LABELS 200000
#define DIM 128
#define NPARTS 391           // ceil(N_NODES/256)
#define NT_TILES 6250        // N_NODES / 16 exactly
#define FG_GRID 2048         // 8 blocks/CU at 48 VGPR -> fully resident, 32 waves/CU

using short8 = __attribute__((ext_vector_type(8))) short;
using f32x2  = __attribute__((ext_vector_type(2))) float;
using f32x4  = __attribute__((ext_vector_type(4))) float;
using u32x2  = __attribute__((ext_vector_type(2))) unsigned;
using u32x4  = __attribute__((ext_vector_type(4))) unsigned;

__device__ __forceinline__ float b2f(short s) {
    union { unsigned u; float f; } c;
    c.u = ((unsigned)(unsigned short)s) << 16;
    return c.f;
}
__device__ __forceinline__ f32x2 b2f2(unsigned u) {
    union { unsigned u; float f; } lo, hi;
    lo.u = u << 16;
    hi.u = u & 0xffff0000u;
    f32x2 r; r[0] = lo.f; r[1] = hi.f;
    return r;
}
__device__ __forceinline__ short f2b(float f) {
    __hip_bfloat16 h = __float2bfloat16(f);
    return *reinterpret_cast<short*>(&h);
}
__device__ __forceinline__ unsigned f2b2u(float x, float y) {
    __hip_bfloat162 h = __float22bfloat162_rn(make_float2(x, y));
    return *reinterpret_cast<unsigned*>(&h);
}

// ---------------- prep: zero cnt + BT1 + u/v projections + cpq ----------------
__global__ void prep_k(const float* __restrict__ W1l, const float* __restrict__ W1r,
                       short* __restrict__ BT1,
                       const float* __restrict__ W2l, const float* __restrict__ W2r,
                       const float* __restrict__ Wlin, const float* __restrict__ b2,
                       float* __restrict__ up, float* __restrict__ uq,
                       float* __restrict__ vp, float* __restrict__ vq,
                       float2* __restrict__ cpq, int* __restrict__ cnt) {
    int b = blockIdx.x;
    int t = threadIdx.x;
    if (b < 128) {
        int i = b * 256 + t;                     // 32768 = 256 rows x 128 k
        int n = i >> 7, k = i & 127;
        float v = (n < 128) ? W1l[k * 128 + n] : W1r[k * 128 + (n - 128)];
        BT1[n * 128 + k] = f2b(v);
    } else if (b == 128) {
        const float* W = (t < 128) ? W2l : W2r;
        int k = t & 127;
        float s0 = 0.f, s1 = 0.f;
        for (int n = 0; n < 128; ++n) {
            float w = W[k * 128 + n];
            s0 += w * Wlin[n];
            s1 += w * Wlin[128 + n];
        }
        if (t < 128) { up[k] = s0; uq[k] = s1; }
        else         { vp[k] = s0; vq[k] = s1; }
    } else if (b == 129) {
        if (t < 64) {
            float p0 = b2[t] * Wlin[t] + b2[t + 64] * Wlin[t + 64];
            float q0 = b2[t] * Wlin[128 + t] + b2[t + 64] * Wlin[192 + t];
#pragma unroll
            for (int m = 1; m <= 32; m <<= 1) {
                p0 += __shfl_xor(p0, m, 64);
                q0 += __shfl_xor(q0, m, 64);
            }
            if (t == 0) *cpq = make_float2(p0, q0);
        }
    } else {
        int i = (b - 130) * 256 + t;
        if (i < N_NODES) cnt[i] = 0;
    }
}

// ---------------- CSR build: count + rank in one atomic pass ----------------
__global__ void count_k(const int* __restrict__ ei, int* __restrict__ cnt,
                        int* __restrict__ rank) {
    int e = blockIdx.x * blockDim.x + threadIdx.x;
    if (e < N_EDGES) rank[e] = atomicAdd(&cnt[ei[N_EDGES + e]], 1);
}

__global__ void scan1_k(const int* __restrict__ cnt, int* __restrict__ rowptr,
                        int* __restrict__ partials) {
    __shared__ int s[256];
    int t = threadIdx.x;
    int i = blockIdx.x * 256 + t;
    int v = (i < N_NODES) ? cnt[i] : 0;
    s[t] = v;
    __syncthreads();
    for (int off = 1; off < 256; off <<= 1) {
        int x = s[t];
        int y = (t >= off) ? s[t - off] : 0;
        __syncthreads();
        s[t] = x + y;
        __syncthreads();
    }
    if (i < N_NODES) rowptr[i] = s[t] - v;      // block-local exclusive
    if (t == 255) partials[blockIdx.x] = s[255];
}

// fused scan2+scan3: every block redundantly scans the partials, applies its base.
__global__ void scanB_k(const int* __restrict__ partials, int* __restrict__ rowptr) {
    __shared__ int s[512];
    __shared__ int base_s;
    int t = threadIdx.x;                         // 512 threads
    int v = (t < NPARTS) ? partials[t] : 0;
    s[t] = v;
    __syncthreads();
    for (int off = 1; off < 512; off <<= 1) {
        int x = s[t];
        int y = (t >= off) ? s[t - off] : 0;
        __syncthreads();
        s[t] = x + y;
        __syncthreads();
    }
    int b = blockIdx.x;
    if (t == 0) base_s = (b > 0) ? s[b - 1] : 0;
    if (b == 0 && t == 0) rowptr[N_NODES] = s[NPARTS - 1];
    __syncthreads();
    if (t < 256) {
        int i = b * 256 + t;
        if (i < N_NODES) rowptr[i] += base_s;
    }
}

// ---------------- fused: adjacency fill slice (atomic-free) + GEMM1 ----------------
// Every block: small grid-stride fill slice, then MFMA gemm. Wave w owns 64 output
// features; 4 waves cover all 256 feats of a 16-node tile.
// D layout: feature = wave*64 + t*16 + quad*4 + r, node = l16.
__global__ __launch_bounds__(256, 4) void fillgemm_k(const int* __restrict__ ei,
                                                     const int* __restrict__ rank,
                                                     const int* __restrict__ rowptr,
                                                     int* __restrict__ adj,
                                                     const float* __restrict__ Af,
                                                     const short* __restrict__ BT,
                                                     short* __restrict__ Hl,
                                                     short* __restrict__ Hr) {
    // fill slice: <=2 edges per thread, scattered stores, no atomics
    for (int e = blockIdx.x * 256 + threadIdx.x; e < N_EDGES; e += FG_GRID * 256) {
        int d = ei[N_EDGES + e];
        adj[rowptr[d] + rank[e]] = ei[e];
    }

    int lane = threadIdx.x & 63;
    int wave = threadIdx.x >> 6;
    int quad = lane >> 4;
    int l16  = lane & 15;
    short* __restrict__ H = (wave < 2) ? Hl : Hr;
    int fbase = (wave & 1) * 64;

    short8 Wf[4][4];
#pragma unroll
    for (int t = 0; t < 4; ++t)
#pragma unroll
        for (int kk = 0; kk < 4; ++kk)
            Wf[t][kk] = *(const short8*)(BT + (wave * 64 + t * 16 + l16) * DIM + kk * 32 + quad * 8);

    for (int s = blockIdx.x; s < NT_TILES; s += FG_GRID) {
        long arow = (long)s * 16 + l16;
        short8 xf[4];
#pragma unroll
        for (int kk = 0; kk < 4; ++kk) {
            f32x4 a0 = *(const f32x4*)(Af + arow * DIM + kk * 32 + quad * 8);
            f32x4 a1 = *(const f32x4*)(Af + arow * DIM + kk * 32 + quad * 8 + 4);
            unsigned* xu = (unsigned*)&xf[kk];
            xu[0] = f2b2u(a0[0], a0[1]);
            xu[1] = f2b2u(a0[2], a0[3]);
            xu[2] = f2b2u(a1[0], a1[1]);
            xu[3] = f2b2u(a1[2], a1[3]);
        }
        f32x4 acc[4];
#pragma unroll
        for (int t = 0; t < 4; ++t)
#pragma unroll
            for (int r = 0; r < 4; ++r) acc[t][r] = 0.f;
#pragma unroll
        for (int kk = 0; kk < 4; ++kk)
#pragma unroll
            for (int t = 0; t < 4; ++t)
                acc[t] = __builtin_amdgcn_mfma_f32_16x16x32_bf16(Wf[t][kk], xf[kk], acc[t], 0, 0, 0);
#pragma unroll
        for (int t = 0; t < 4; ++t) {
            u32x2 o;
            o[0] = f2b2u(acc[t][0], acc[t][1]);
            o[1] = f2b2u(acc[t][2], acc[t][3]);
            *(u32x2*)(H + arow * DIM + fbase + t * 16 + quad * 4) = o;
        }
    }
}

// -------- gather-mean: one wave per node, 4 edge-rows in flight, 16B/lane --------
__device__ __forceinline__ void gather_mean(const short* __restrict__ Hl,
                                            const int* __restrict__ rowptr,
                                            const int* __restrict__ adj,
                                            int node, int lane, f32x2 sum[4], float& inv) {
    int g  = lane >> 4;
    int f0 = (lane & 15) << 3;
    int beg = rowptr[node];
    int deg = rowptr[node + 1] - beg;
#pragma unroll
    for (int d = 0; d < 4; ++d) { sum[d][0] = 0.f; sum[d][1] = 0.f; }

    int av = (lane < deg) ? adj[beg + lane] : 0;
    int degc = deg < 64 ? deg : 64;

    u32x4 h0;
    bool v0 = false;
    if (degc > 0) {
        int idx = __shfl(av, g, 64);
        v0 = g < degc;
        if (v0) h0 = *(const u32x4*)(Hl + (long)idx * DIM + f0);
    }
    for (int e0 = 4; e0 < degc; e0 += 4) {
        int idx = __shfl(av, e0 + g, 64);
        bool v1 = (e0 + g) < degc;
        u32x4 h1;
        if (v1) h1 = *(const u32x4*)(Hl + (long)idx * DIM + f0);
        if (v0) {
#pragma unroll
            for (int d = 0; d < 4; ++d) sum[d] += b2f2(h0[d]);
        }
        h0 = h1; v0 = v1;
    }
    if (v0) {
#pragma unroll
        for (int d = 0; d < 4; ++d) sum[d] += b2f2(h0[d]);
    }
    for (int e0 = 64; e0 < deg; e0 += 4) {
        int e = e0 + g;
        if (e < deg) {
            int idx = adj[beg + e];
            u32x4 h = *(const u32x4*)(Hl + (long)idx * DIM + f0);
#pragma unroll
            for (int d = 0; d < 4; ++d) sum[d] += b2f2(h[d]);
        }
    }
#pragma unroll
    for (int d = 0; d < 4; ++d)
#pragma unroll
        for (int c = 0; c < 2; ++c) {
            sum[d][c] += __shfl_xor(sum[d][c], 16, 64);
            sum[d][c] += __shfl_xor(sum[d][c], 32, 64);
        }
    inv = deg > 0 ? 1.f / (float)deg : 0.f;
}

// layer-1 agg fused with layer-2 projections (packed f32x2 math in the dots)
__global__ void agg1_k(const short* __restrict__ Hl, const short* __restrict__ Hr,
                       const int* __restrict__ rowptr, const int* __restrict__ adj,
                       const float* __restrict__ b1,
                       const float* __restrict__ up, const float* __restrict__ uq,
                       const float* __restrict__ vp, const float* __restrict__ vq,
                       float2* __restrict__ S, float2* __restrict__ T) {
    int lane = threadIdx.x & 63;
    int node = blockIdx.x * 4 + (threadIdx.x >> 6);
    int f0 = (lane & 15) << 3;
    if (node >= N_NODES) return;

    f32x2 sum[4]; float inv;
    gather_mean(Hl, rowptr, adj, node, lane, sum, inv);

    u32x4 hru = *(const u32x4*)(Hr + (long)node * DIM + f0);
    f32x2 x2[4];
#pragma unroll
    for (int d = 0; d < 4; ++d) {
        f32x2 hr2 = b2f2(hru[d]);
        f32x2 bb  = *(const f32x2*)(b1 + f0 + 2 * d);
        f32x2 v   = sum[d] * inv + hr2 + bb;
        x2[d][0] = fmaxf(v[0], 0.f);
        x2[d][1] = fmaxf(v[1], 0.f);
    }

    f32x2 ap2 = {0.f, 0.f}, aq2 = {0.f, 0.f}, tp2 = {0.f, 0.f}, tq2 = {0.f, 0.f};
#pragma unroll
    for (int d = 0; d < 4; ++d) {
        f32x2 u0 = *(const f32x2*)(up + f0 + 2 * d);
        f32x2 u1 = *(const f32x2*)(uq + f0 + 2 * d);
        f32x2 w0 = *(const f32x2*)(vp + f0 + 2 * d);
        f32x2 w1 = *(const f32x2*)(vq + f0 + 2 * d);
        ap2 += x2[d] * u0;
        aq2 += x2[d] * u1;
        tp2 += x2[d] * w0;
        tq2 += x2[d] * w1;
    }
    float ap = ap2[0] + ap2[1], aq = aq2[0] + aq2[1];
    float tp = tp2[0] + tp2[1], tq = tq2[0] + tq2[1];
#pragma unroll
    for (int m = 1; m <= 8; m <<= 1) {
        ap += __shfl_xor(ap, m, 64);
        aq += __shfl_xor(aq, m, 64);
        tp += __shfl_xor(tp, m, 64);
        tq += __shfl_xor(tq, m, 64);
    }
    if (lane == 0) {
        S[node] = make_float2(ap, aq);
        T[node] = make_float2(tp, tq);
    }
}

// layer-2: p[n] = mean_nbrs(S.x) + T.x + c.x (8B gather per edge)
__global__ void agg2_k(const int* __restrict__ rowptr, const int* __restrict__ adj,
                       const float2* __restrict__ S, const float2* __restrict__ T,
                       const float2* __restrict__ cpq,
                       float* __restrict__ p, float* __restrict__ q) {
    int lane = threadIdx.x & 63;
    int wavei = blockIdx.x * 4 + (threadIdx.x >> 6);
    int slot = lane & 3;
    int node = wavei * 16 + (lane >> 2);
    if (node >= N_NODES) return;
    int beg = rowptr[node], end = rowptr[node + 1];
    float sp = 0.f, sq = 0.f;
    for (int e = beg + slot; e < end; e += 4) {
        float2 v = S[adj[e]];
        sp += v.x; sq += v.y;
    }
    sp += __shfl_xor(sp, 1, 64); sp += __shfl_xor(sp, 2, 64);
    sq += __shfl_xor(sq, 1, 64); sq += __shfl_xor(sq, 2, 64);
    if (slot == 0) {
        int deg = end - beg;
        float inv = deg > 0 ? 1.f / (float)deg : 0.f;
        float2 t = T[node];
        float2 c = *cpq;
        p[node] = sp * inv + t.x + c.x;
        q[node] = sq * inv + t.y + c.y;
    }
}

__global__ void out_k(const int* __restrict__ eli, const float* __restrict__ p,
                      const float* __restrict__ q, const float* __restrict__ blin,
                      float* __restrict__ out) {
    int i = blockIdx.x * blockDim.x + threadIdx.x;
    if (i < N_LABELS) out[i] = p[eli[i]] + q[eli[N_LABELS + i]] + blin[0];
}

// ---------------- launch ----------------

extern "C" void kernel_launch(void* const* d_in, const int* in_sizes, int n_in,
                              void* d_out, int out_size, void* d_ws, size_t ws_size,
                              hipStream_t stream) {
    const int*   edge_index = (const int*)d_in[0];
    const int*   eli        = (const int*)d_in[1];
    const float* emb        = (const float*)d_in[2];
    const float* W1l        = (const float*)d_in[3];
    const float* b1         = (const float*)d_in[4];
    const float* W1r        = (const float*)d_in[5];
    const float* W2l        = (const float*)d_in[6];
    const float* b2         = (const float*)d_in[7];
    const float* W2r        = (const float*)d_in[8];
    const float* Wlin       = (const float*)d_in[9];
    const float* blin       = (const float*)d_in[10];
    float* out = (float*)d_out;

    char* ws = (char*)d_ws;
    size_t off = 0;
    auto alloc = [&](size_t bytes) -> void* {
        off = (off + 255) & ~(size_t)255;
        void* ptr = ws + off;
        off += bytes;
        return ptr;
    };

    short* Hl  = (short*)alloc((size_t)N_NODES * DIM * 2);
    short* Hr  = (short*)alloc((size_t)N_NODES * DIM * 2);
    short* BT1 = (short*)alloc(256 * 128 * 2);
    float* up = (float*)alloc(128 * 4);
    float* uq = (float*)alloc(128 * 4);
    float* vp = (float*)alloc(128 * 4);
    float* vq = (float*)alloc(128 * 4);
    float2* cpq = (float2*)alloc(8);
    int* cnt      = (int*)alloc((size_t)N_NODES * 4);
    int* rowptr   = (int*)alloc((size_t)(N_NODES + 1) * 4);
    int* rank     = (int*)alloc((size_t)N_EDGES * 4);
    int* adj      = (int*)alloc((size_t)N_EDGES * 4);
    int* partials = (int*)alloc(NPARTS * 4);
    float2* S     = (float2*)alloc((size_t)N_NODES * 8);
    float2* T     = (float2*)alloc((size_t)N_NODES * 8);
    float* p      = (float*)alloc((size_t)N_NODES * 4);
    float* q      = (float*)alloc((size_t)N_NODES * 4);

    // prep (weights + projections + cnt zero)
    prep_k<<<130 + NPARTS, 256, 0, stream>>>(W1l, W1r, BT1, W2l, W2r, Wlin, b2,
                                             up, uq, vp, vq, cpq, cnt);
    // CSR: count + rank (single atomic pass), then scan
    count_k<<<(N_EDGES + 255) / 256, 256, 0, stream>>>(edge_index, cnt, rank);
    scan1_k<<<NPARTS, 256, 0, stream>>>(cnt, rowptr, partials);
    scanB_k<<<NPARTS, 512, 0, stream>>>(partials, rowptr);

    // adjacency fill (atomic-free slice per block) + layer-1 GEMM
    fillgemm_k<<<FG_GRID, 256, 0, stream>>>(edge_index, rank, rowptr, adj, emb, BT1, Hl, Hr);

    // layer-1 aggregation fused with layer-2 projections
    agg1_k<<<N_NODES / 4, 256, 0, stream>>>(Hl, Hr, rowptr, adj, b1, up, uq, vp, vq, S, T);

    // layer-2 (8B-per-edge gather) + predictor
    agg2_k<<<(N_NODES + 63) / 64, 256, 0, stream>>>(rowptr, adj, S, T, cpq, p, q);
    out_k<<<(N_LABELS + 255) / 256, 256, 0, stream>>>(eli, p, q, blin, out);
}

// Round 13
// 233.224 us; speedup vs baseline: 1.1068x; 1.1068x over previous
//
#include <hip/hip_runtime.h>
#include <hip/hip_bf16.h>

#define N_NODES 100000
#define N_EDGES 600000
#define N_LABELS 200000
#define DIM 128
#define NPARTS 391           // ceil(N_NODES/256)
#define MT 64                // gemm macrotile rows
#define NMT 1563             // ceil(N_NODES/64)
#define FG_GRID 768          // 3 blocks/CU (LDS-limited), all resident
#define LDA 136              // lA row stride in shorts (128 + 8 pad; 272B = 16-aligned, uniform banks)
#define LDC 280              // lC row stride in shorts (256 + 24 pad; 560B = 16-aligned, uniform banks)

using short8 = __attribute__((ext_vector_type(8))) short;
using f32x2  = __attribute__((ext_vector_type(2))) float;
using f32x4  = __attribute__((ext_vector_type(4))) float;
using u32x2  = __attribute__((ext_vector_type(2))) unsigned;
using u32x4  = __attribute__((ext_vector_type(4))) unsigned;

__device__ __forceinline__ float b2f(short s) {
    union { unsigned u; float f; } c;
    c.u = ((unsigned)(unsigned short)s) << 16;
    return c.f;
}
__device__ __forceinline__ f32x2 b2f2(unsigned u) {
    union { unsigned u; float f; } lo, hi;
    lo.u = u << 16;
    hi.u = u & 0xffff0000u;
    f32x2 r; r[0] = lo.f; r[1] = hi.f;
    return r;
}
__device__ __forceinline__ short f2b(float f) {
    __hip_bfloat16 h = __float2bfloat16(f);
    return *reinterpret_cast<short*>(&h);
}
__device__ __forceinline__ unsigned f2b2u(float x, float y) {
    __hip_bfloat162 h = __float22bfloat162_rn(make_float2(x, y));
    return *reinterpret_cast<unsigned*>(&h);
}

// ---------------- prep: zero cnt + BT1 + u/v projections + cpq ----------------
__global__ void prep_k(const float* __restrict__ W1l, const float* __restrict__ W1r,
                       short* __restrict__ BT1,
                       const float* __restrict__ W2l, const float* __restrict__ W2r,
                       const float* __restrict__ Wlin, const float* __restrict__ b2,
                       float* __restrict__ up, float* __restrict__ uq,
                       float* __restrict__ vp, float* __restrict__ vq,
                       float2* __restrict__ cpq, int* __restrict__ cnt) {
    int b = blockIdx.x;
    int t = threadIdx.x;
    if (b < 128) {
        int i = b * 256 + t;                     // 32768 = 256 rows x 128 k
        int n = i >> 7, k = i & 127;
        float v = (n < 128) ? W1l[k * 128 + n] : W1r[k * 128 + (n - 128)];
        BT1[n * 128 + k] = f2b(v);
    } else if (b == 128) {
        const float* W = (t < 128) ? W2l : W2r;
        int k = t & 127;
        float s0 = 0.f, s1 = 0.f;
        for (int n = 0; n < 128; ++n) {
            float w = W[k * 128 + n];
            s0 += w * Wlin[n];
            s1 += w * Wlin[128 + n];
        }
        if (t < 128) { up[k] = s0; uq[k] = s1; }
        else         { vp[k] = s0; vq[k] = s1; }
    } else if (b == 129) {
        if (t < 64) {
            float p0 = b2[t] * Wlin[t] + b2[t + 64] * Wlin[t + 64];
            float q0 = b2[t] * Wlin[128 + t] + b2[t + 64] * Wlin[192 + t];
#pragma unroll
            for (int m = 1; m <= 32; m <<= 1) {
                p0 += __shfl_xor(p0, m, 64);
                q0 += __shfl_xor(q0, m, 64);
            }
            if (t == 0) *cpq = make_float2(p0, q0);
        }
    } else {
        int i = (b - 130) * 256 + t;
        if (i < N_NODES) cnt[i] = 0;
    }
}

// ---------------- CSR build: count + rank in one atomic pass ----------------
__global__ void count_k(const int* __restrict__ ei, int* __restrict__ cnt,
                        int* __restrict__ rank) {
    int e = blockIdx.x * blockDim.x + threadIdx.x;
    if (e < N_EDGES) rank[e] = atomicAdd(&cnt[ei[N_EDGES + e]], 1);
}

__global__ void scan1_k(const int* __restrict__ cnt, int* __restrict__ rowptr,
                        int* __restrict__ partials) {
    __shared__ int s[256];
    int t = threadIdx.x;
    int i = blockIdx.x * 256 + t;
    int v = (i < N_NODES) ? cnt[i] : 0;
    s[t] = v;
    __syncthreads();
    for (int off = 1; off < 256; off <<= 1) {
        int x = s[t];
        int y = (t >= off) ? s[t - off] : 0;
        __syncthreads();
        s[t] = x + y;
        __syncthreads();
    }
    if (i < N_NODES) rowptr[i] = s[t] - v;      // block-local exclusive
    if (t == 255) partials[blockIdx.x] = s[255];
}

// fused scan2+scan3: every block redundantly scans the partials, applies its base.
__global__ void scanB_k(const int* __restrict__ partials, int* __restrict__ rowptr) {
    __shared__ int s[512];
    __shared__ int base_s;
    int t = threadIdx.x;                         // 512 threads
    int v = (t < NPARTS) ? partials[t] : 0;
    s[t] = v;
    __syncthreads();
    for (int off = 1; off < 512; off <<= 1) {
        int x = s[t];
        int y = (t >= off) ? s[t - off] : 0;
        __syncthreads();
        s[t] = x + y;
        __syncthreads();
    }
    int b = blockIdx.x;
    if (t == 0) base_s = (b > 0) ? s[b - 1] : 0;
    if (b == 0 && t == 0) rowptr[N_NODES] = s[NPARTS - 1];
    __syncthreads();
    if (t < 256) {
        int i = b * 256 + t;
        if (i < N_NODES) rowptr[i] += base_s;
    }
}

// ---------------- fused: adjacency fill slice + LDS-staged GEMM1 ----------------
// Per 64-row macrotile: stage A (coalesced f32 reads -> bf16 LDS), MFMA compute
// (weights resident, A-frags from LDS), stage C in LDS, coalesced linear writeout.
// D layout: feature = wave*64 + t*16 + quad*4 + r, node-row = l16.
__global__ __launch_bounds__(256, 3) void fillgemm_k(const int* __restrict__ ei,
                                                     const int* __restrict__ rank,
                                                     const int* __restrict__ rowptr,
                                                     int* __restrict__ adj,
                                                     const float* __restrict__ Af,
                                                     const short* __restrict__ BT,
                                                     short* __restrict__ Hl,
                                                     short* __restrict__ Hr) {
    __shared__ short lA[MT * LDA];
    __shared__ short lC[MT * LDC];
    int tid = threadIdx.x;

    // fill slice: atomic-free scatter
    for (int e = blockIdx.x * 256 + tid; e < N_EDGES; e += FG_GRID * 256) {
        int d = ei[N_EDGES + e];
        adj[rowptr[d] + rank[e]] = ei[e];
    }

    int lane = tid & 63;
    int wave = tid >> 6;
    int quad = lane >> 4;
    int l16  = lane & 15;

    // resident weight fragments: wave owns feats [wave*64, wave*64+64)
    short8 Wf[4][4];
#pragma unroll
    for (int t = 0; t < 4; ++t)
#pragma unroll
        for (int kk = 0; kk < 4; ++kk)
            Wf[t][kk] = *(const short8*)(BT + (wave * 64 + t * 16 + l16) * DIM + kk * 32 + quad * 8);

    for (int mt = blockIdx.x; mt < NMT; mt += FG_GRID) {
        long base = (long)mt * MT;

        // ---- stage A: 2048 f32x4 chunks, 8 per thread, coalesced ----
        __syncthreads();                          // protect lA/lC from previous iter
#pragma unroll
        for (int i = 0; i < 8; ++i) {
            int c = tid + i * 256;                // 0..2047
            int row = c >> 5;                     // 32 chunks (512B) per row
            int k4 = (c & 31) << 2;               // float offset in row
            long grow = base + row;
            f32x4 a;
            if (grow < N_NODES) a = *(const f32x4*)(Af + grow * DIM + k4);
            else { a[0] = 0.f; a[1] = 0.f; a[2] = 0.f; a[3] = 0.f; }
            u32x2 o;
            o[0] = f2b2u(a[0], a[1]);
            o[1] = f2b2u(a[2], a[3]);
            *(u32x2*)(lA + row * LDA + k4) = o;
        }
        __syncthreads();

        // ---- compute: 4 subtiles of 16 rows ----
#pragma unroll
        for (int sub = 0; sub < 4; ++sub) {
            int r0 = sub * 16;
            short8 xf[4];
#pragma unroll
            for (int kk = 0; kk < 4; ++kk)
                xf[kk] = *(const short8*)(lA + (r0 + l16) * LDA + kk * 32 + quad * 8);
            f32x4 acc[4];
#pragma unroll
            for (int t = 0; t < 4; ++t)
#pragma unroll
                for (int r = 0; r < 4; ++r) acc[t][r] = 0.f;
#pragma unroll
            for (int kk = 0; kk < 4; ++kk)
#pragma unroll
                for (int t = 0; t < 4; ++t)
                    acc[t] = __builtin_amdgcn_mfma_f32_16x16x32_bf16(Wf[t][kk], xf[kk], acc[t], 0, 0, 0);
#pragma unroll
            for (int t = 0; t < 4; ++t) {
                u32x2 o;
                o[0] = f2b2u(acc[t][0], acc[t][1]);
                o[1] = f2b2u(acc[t][2], acc[t][3]);
                *(u32x2*)(lC + (r0 + l16) * LDC + wave * 64 + t * 16 + quad * 4) = o;
            }
        }
        __syncthreads();

        // ---- writeout: linear, fully coalesced (1KB contiguous per wave-instr) ----
#pragma unroll
        for (int half = 0; half < 2; ++half) {
            short* __restrict__ H = half ? Hr : Hl;
#pragma unroll
            for (int i = 0; i < 4; ++i) {
                int c2 = tid + i * 256;           // 0..1023
                int row = c2 >> 4;                // 16 chunks (256B) per row-half
                int f8 = (c2 & 15) << 3;          // feat offset
                long grow = base + row;
                if (grow < N_NODES) {
                    short8 v = *(const short8*)(lC + row * LDC + half * 128 + f8);
                    *(short8*)(H + grow * DIM + f8) = v;
                }
            }
        }
    }
}

// -------- gather-mean: one wave per node, 4 edge-rows in flight, 16B/lane --------
__device__ __forceinline__ void gather_mean(const short* __restrict__ Hl,
                                            const int* __restrict__ rowptr,
                                            const int* __restrict__ adj,
                                            int node, int lane, f32x2 sum[4], float& inv) {
    int g  = lane >> 4;
    int f0 = (lane & 15) << 3;
    int beg = rowptr[node];
    int deg = rowptr[node + 1] - beg;
#pragma unroll
    for (int d = 0; d < 4; ++d) { sum[d][0] = 0.f; sum[d][1] = 0.f; }

    int av = (lane < deg) ? adj[beg + lane] : 0;
    int degc = deg < 64 ? deg : 64;

    u32x4 h0;
    bool v0 = false;
    if (degc > 0) {
        int idx = __shfl(av, g, 64);
        v0 = g < degc;
        if (v0) h0 = *(const u32x4*)(Hl + (long)idx * DIM + f0);
    }
    for (int e0 = 4; e0 < degc; e0 += 4) {
        int idx = __shfl(av, e0 + g, 64);
        bool v1 = (e0 + g) < degc;
        u32x4 h1;
        if (v1) h1 = *(const u32x4*)(Hl + (long)idx * DIM + f0);
        if (v0) {
#pragma unroll
            for (int d = 0; d < 4; ++d) sum[d] += b2f2(h0[d]);
        }
        h0 = h1; v0 = v1;
    }
    if (v0) {
#pragma unroll
        for (int d = 0; d < 4; ++d) sum[d] += b2f2(h0[d]);
    }
    for (int e0 = 64; e0 < deg; e0 += 4) {
        int e = e0 + g;
        if (e < deg) {
            int idx = adj[beg + e];
            u32x4 h = *(const u32x4*)(Hl + (long)idx * DIM + f0);
#pragma unroll
            for (int d = 0; d < 4; ++d) sum[d] += b2f2(h[d]);
        }
    }
#pragma unroll
    for (int d = 0; d < 4; ++d)
#pragma unroll
        for (int c = 0; c < 2; ++c) {
            sum[d][c] += __shfl_xor(sum[d][c], 16, 64);
            sum[d][c] += __shfl_xor(sum[d][c], 32, 64);
        }
    inv = deg > 0 ? 1.f / (float)deg : 0.f;
}

// layer-1 agg fused with layer-2 projections (packed f32x2 math in the dots)
__global__ void agg1_k(const short* __restrict__ Hl, const short* __restrict__ Hr,
                       const int* __restrict__ rowptr, const int* __restrict__ adj,
                       const float* __restrict__ b1,
                       const float* __restrict__ up, const float* __restrict__ uq,
                       const float* __restrict__ vp, const float* __restrict__ vq,
                       float2* __restrict__ S, float2* __restrict__ T) {
    int lane = threadIdx.x & 63;
    int node = blockIdx.x * 4 + (threadIdx.x >> 6);
    int f0 = (lane & 15) << 3;
    if (node >= N_NODES) return;

    f32x2 sum[4]; float inv;
    gather_mean(Hl, rowptr, adj, node, lane, sum, inv);

    u32x4 hru = *(const u32x4*)(Hr + (long)node * DIM + f0);
    f32x2 x2[4];
#pragma unroll
    for (int d = 0; d < 4; ++d) {
        f32x2 hr2 = b2f2(hru[d]);
        f32x2 bb  = *(const f32x2*)(b1 + f0 + 2 * d);
        f32x2 v   = sum[d] * inv + hr2 + bb;
        x2[d][0] = fmaxf(v[0], 0.f);
        x2[d][1] = fmaxf(v[1], 0.f);
    }

    f32x2 ap2 = {0.f, 0.f}, aq2 = {0.f, 0.f}, tp2 = {0.f, 0.f}, tq2 = {0.f, 0.f};
#pragma unroll
    for (int d = 0; d < 4; ++d) {
        f32x2 u0 = *(const f32x2*)(up + f0 + 2 * d);
        f32x2 u1 = *(const f32x2*)(uq + f0 + 2 * d);
        f32x2 w0 = *(const f32x2*)(vp + f0 + 2 * d);
        f32x2 w1 = *(const f32x2*)(vq + f0 + 2 * d);
        ap2 += x2[d] * u0;
        aq2 += x2[d] * u1;
        tp2 += x2[d] * w0;
        tq2 += x2[d] * w1;
    }
    float ap = ap2[0] + ap2[1], aq = aq2[0] + aq2[1];
    float tp = tp2[0] + tp2[1], tq = tq2[0] + tq2[1];
#pragma unroll
    for (int m = 1; m <= 8; m <<= 1) {
        ap += __shfl_xor(ap, m, 64);
        aq += __shfl_xor(aq, m, 64);
        tp += __shfl_xor(tp, m, 64);
        tq += __shfl_xor(tq, m, 64);
    }
    if (lane == 0) {
        S[node] = make_float2(ap, aq);
        T[node] = make_float2(tp, tq);
    }
}

// layer-2: p[n] = mean_nbrs(S.x) + T.x + c.x (8B gather per edge)
__global__ void agg2_k(const int* __restrict__ rowptr, const int* __restrict__ adj,
                       const float2* __restrict__ S, const float2* __restrict__ T,
                       const float2* __restrict__ cpq,
                       float* __restrict__ p, float* __restrict__ q) {
    int lane = threadIdx.x & 63;
    int wavei = blockIdx.x * 4 + (threadIdx.x >> 6);
    int slot = lane & 3;
    int node = wavei * 16 + (lane >> 2);
    if (node >= N_NODES) return;
    int beg = rowptr[node], end = rowptr[node + 1];
    float sp = 0.f, sq = 0.f;
    for (int e = beg + slot; e < end; e += 4) {
        float2 v = S[adj[e]];
        sp += v.x; sq += v.y;
    }
    sp += __shfl_xor(sp, 1, 64); sp += __shfl_xor(sp, 2, 64);
    sq += __shfl_xor(sq, 1, 64); sq += __shfl_xor(sq, 2, 64);
    if (slot == 0) {
        int deg = end - beg;
        float inv = deg > 0 ? 1.f / (float)deg : 0.f;
        float2 t = T[node];
        float2 c = *cpq;
        p[node] = sp * inv + t.x + c.x;
        q[node] = sq * inv + t.y + c.y;
    }
}

__global__ void out_k(const int* __restrict__ eli, const float* __restrict__ p,
                      const float* __restrict__ q, const float* __restrict__ blin,
                      float* __restrict__ out) {
    int i = blockIdx.x * blockDim.x + threadIdx.x;
    if (i < N_LABELS) out[i] = p[eli[i]] + q[eli[N_LABELS + i]] + blin[0];
}

// ---------------- launch ----------------

extern "C" void kernel_launch(void* const* d_in, const int* in_sizes, int n_in,
                              void* d_out, int out_size, void* d_ws, size_t ws_size,
                              hipStream_t stream) {
    const int*   edge_index = (const int*)d_in[0];
    const int*   eli        = (const int*)d_in[1];
    const float* emb        = (const float*)d_in[2];
    const float* W1l        = (const float*)d_in[3];
    const float* b1         = (const float*)d_in[4];
    const float* W1r        = (const float*)d_in[5];
    const float* W2l        = (const float*)d_in[6];
    const float* b2         = (const float*)d_in[7];
    const float* W2r        = (const float*)d_in[8];
    const float* Wlin       = (const float*)d_in[9];
    const float* blin       = (const float*)d_in[10];
    float* out = (float*)d_out;

    char* ws = (char*)d_ws;
    size_t off = 0;
    auto alloc = [&](size_t bytes) -> void* {
        off = (off + 255) & ~(size_t)255;
        void* ptr = ws + off;
        off += bytes;
        return ptr;
    };

    short* Hl  = (short*)alloc((size_t)N_NODES * DIM * 2);
    short* Hr  = (short*)alloc((size_t)N_NODES * DIM * 2);
    short* BT1 = (short*)alloc(256 * 128 * 2);
    float* up = (float*)alloc(128 * 4);
    float* uq = (float*)alloc(128 * 4);
    float* vp = (float*)alloc(128 * 4);
    float* vq = (float*)alloc(128 * 4);
    float2* cpq = (float2*)alloc(8);
    int* cnt      = (int*)alloc((size_t)N_NODES * 4);
    int* rowptr   = (int*)alloc((size_t)(N_NODES + 1) * 4);
    int* rank     = (int*)alloc((size_t)N_EDGES * 4);
    int* adj      = (int*)alloc((size_t)N_EDGES * 4);
    int* partials = (int*)alloc(NPARTS * 4);
    float2* S     = (float2*)alloc((size_t)N_NODES * 8);
    float2* T     = (float2*)alloc((size_t)N_NODES * 8);
    float* p      = (float*)alloc((size_t)N_NODES * 4);
    float* q      = (float*)alloc((size_t)N_NODES * 4);

    // prep (weights + projections + cnt zero)
    prep_k<<<130 + NPARTS, 256, 0, stream>>>(W1l, W1r, BT1, W2l, W2r, Wlin, b2,
                                             up, uq, vp, vq, cpq, cnt);
    // CSR: count + rank (single atomic pass), then scan
    count_k<<<(N_EDGES + 255) / 256, 256, 0, stream>>>(edge_index, cnt, rank);
    scan1_k<<<NPARTS, 256, 0, stream>>>(cnt, rowptr, partials);
    scanB_k<<<NPARTS, 512, 0, stream>>>(partials, rowptr);

    // adjacency fill (atomic-free slice per block) + LDS-staged layer-1 GEMM
    fillgemm_k<<<FG_GRID, 256, 0, stream>>>(edge_index, rank, rowptr, adj, emb, BT1, Hl, Hr);

    // layer-1 aggregation fused with layer-2 projections
    agg1_k<<<N_NODES / 4, 256, 0, stream>>>(Hl, Hr, rowptr, adj, b1, up, uq, vp, vq, S, T);

    // layer-2 (8B-per-edge gather) + predictor
    agg2_k<<<(N_NODES + 63) / 64, 256, 0, stream>>>(rowptr, adj, S, T, cpq, p, q);
    out_k<<<(N_LABELS + 255) / 256, 256, 0, stream>>>(eli, p, q, blin, out);
}

// Round 14
// 207.754 us; speedup vs baseline: 1.2425x; 1.1226x over previous
//
#include <hip/hip_runtime.h>
#include <hip/hip_bf16.h>

#define N_NODES 100000
#define N_EDGES 600000
#define N_LABELS 200000
#define DIM 128
#define NPARTS 391           // ceil(N_NODES/256)
#define MT 64                // gemm macrotile rows
#define NMT 1563             // ceil(N_NODES/64)
#define FG_GRID 768          // 3 blocks/CU (LDS-limited), all resident
#define LDA 136              // lA row stride in shorts
#define LDC 280              // lC row stride in shorts
#define CNT_BLOCKS 2344      // ceil(N_EDGES/256) for the count slice in prep

using short8 = __attribute__((ext_vector_type(8))) short;
using f32x2  = __attribute__((ext_vector_type(2))) float;
using f32x4  = __attribute__((ext_vector_type(4))) float;
using u32x2  = __attribute__((ext_vector_type(2))) unsigned;
using u32x4  = __attribute__((ext_vector_type(4))) unsigned;

__device__ __forceinline__ float b2f(short s) {
    union { unsigned u; float f; } c;
    c.u = ((unsigned)(unsigned short)s) << 16;
    return c.f;
}
__device__ __forceinline__ f32x2 b2f2(unsigned u) {
    union { unsigned u; float f; } lo, hi;
    lo.u = u << 16;
    hi.u = u & 0xffff0000u;
    f32x2 r; r[0] = lo.f; r[1] = hi.f;
    return r;
}
__device__ __forceinline__ short f2b(float f) {
    __hip_bfloat16 h = __float2bfloat16(f);
    return *reinterpret_cast<short*>(&h);
}
__device__ __forceinline__ unsigned f2b2u(float x, float y) {
    __hip_bfloat162 h = __float22bfloat162_rn(make_float2(x, y));
    return *reinterpret_cast<unsigned*>(&h);
}

// ------- prep: BT1 + projections + cpq  ||  count+rank (cnt pre-zeroed by memset) -------
__global__ void prep_k(const float* __restrict__ W1l, const float* __restrict__ W1r,
                       short* __restrict__ BT1,
                       const float* __restrict__ W2l, const float* __restrict__ W2r,
                       const float* __restrict__ Wlin, const float* __restrict__ b2,
                       float* __restrict__ up, float* __restrict__ uq,
                       float* __restrict__ vp, float* __restrict__ vq,
                       float2* __restrict__ cpq,
                       const int* __restrict__ ei, int* __restrict__ cnt,
                       int* __restrict__ rank) {
    int b = blockIdx.x;
    int t = threadIdx.x;
    if (b < 128) {
        int i = b * 256 + t;                     // 32768 = 256 rows x 128 k
        int n = i >> 7, k = i & 127;
        float v = (n < 128) ? W1l[k * 128 + n] : W1r[k * 128 + (n - 128)];
        BT1[n * 128 + k] = f2b(v);
    } else if (b == 128) {
        const float* W = (t < 128) ? W2l : W2r;
        int k = t & 127;
        float s0 = 0.f, s1 = 0.f;
        for (int n = 0; n < 128; ++n) {
            float w = W[k * 128 + n];
            s0 += w * Wlin[n];
            s1 += w * Wlin[128 + n];
        }
        if (t < 128) { up[k] = s0; uq[k] = s1; }
        else         { vp[k] = s0; vq[k] = s1; }
    } else if (b == 129) {
        if (t < 64) {
            float p0 = b2[t] * Wlin[t] + b2[t + 64] * Wlin[t + 64];
            float q0 = b2[t] * Wlin[128 + t] + b2[t + 64] * Wlin[192 + t];
#pragma unroll
            for (int m = 1; m <= 32; m <<= 1) {
                p0 += __shfl_xor(p0, m, 64);
                q0 += __shfl_xor(q0, m, 64);
            }
            if (t == 0) *cpq = make_float2(p0, q0);
        }
    } else {
        int e = (b - 130) * 256 + t;
        if (e < N_EDGES) rank[e] = atomicAdd(&cnt[ei[N_EDGES + e]], 1);
    }
}

__global__ void scan1_k(const int* __restrict__ cnt, int* __restrict__ rowptr,
                        int* __restrict__ partials) {
    __shared__ int s[256];
    int t = threadIdx.x;
    int i = blockIdx.x * 256 + t;
    int v = (i < N_NODES) ? cnt[i] : 0;
    s[t] = v;
    __syncthreads();
    for (int off = 1; off < 256; off <<= 1) {
        int x = s[t];
        int y = (t >= off) ? s[t - off] : 0;
        __syncthreads();
        s[t] = x + y;
        __syncthreads();
    }
    if (i < N_NODES) rowptr[i] = s[t] - v;      // block-local exclusive
    if (t == 255) partials[blockIdx.x] = s[255];
}

// fused scan2+scan3: every block redundantly scans the partials, applies its base.
__global__ void scanB_k(const int* __restrict__ partials, int* __restrict__ rowptr) {
    __shared__ int s[512];
    __shared__ int base_s;
    int t = threadIdx.x;                         // 512 threads
    int v = (t < NPARTS) ? partials[t] : 0;
    s[t] = v;
    __syncthreads();
    for (int off = 1; off < 512; off <<= 1) {
        int x = s[t];
        int y = (t >= off) ? s[t - off] : 0;
        __syncthreads();
        s[t] = x + y;
        __syncthreads();
    }
    int b = blockIdx.x;
    if (t == 0) base_s = (b > 0) ? s[b - 1] : 0;
    if (b == 0 && t == 0) rowptr[N_NODES] = s[NPARTS - 1];
    __syncthreads();
    if (t < 256) {
        int i = b * 256 + t;
        if (i < N_NODES) rowptr[i] += base_s;
    }
}

// ---------------- fused: adjacency fill slice + LDS-staged GEMM1 ----------------
__global__ __launch_bounds__(256, 3) void fillgemm_k(const int* __restrict__ ei,
                                                     const int* __restrict__ rank,
                                                     const int* __restrict__ rowptr,
                                                     int* __restrict__ adj,
                                                     const float* __restrict__ Af,
                                                     const short* __restrict__ BT,
                                                     short* __restrict__ Hl,
                                                     short* __restrict__ Hr) {
    __shared__ short lA[MT * LDA];
    __shared__ short lC[MT * LDC];
    int tid = threadIdx.x;

    // fill slice: atomic-free scatter
    for (int e = blockIdx.x * 256 + tid; e < N_EDGES; e += FG_GRID * 256) {
        int d = ei[N_EDGES + e];
        adj[rowptr[d] + rank[e]] = ei[e];
    }

    int lane = tid & 63;
    int wave = tid >> 6;
    int quad = lane >> 4;
    int l16  = lane & 15;

    short8 Wf[4][4];
#pragma unroll
    for (int t = 0; t < 4; ++t)
#pragma unroll
        for (int kk = 0; kk < 4; ++kk)
            Wf[t][kk] = *(const short8*)(BT + (wave * 64 + t * 16 + l16) * DIM + kk * 32 + quad * 8);

    for (int mt = blockIdx.x; mt < NMT; mt += FG_GRID) {
        long base = (long)mt * MT;

        __syncthreads();
#pragma unroll
        for (int i = 0; i < 8; ++i) {
            int c = tid + i * 256;
            int row = c >> 5;
            int k4 = (c & 31) << 2;
            long grow = base + row;
            f32x4 a;
            if (grow < N_NODES) a = *(const f32x4*)(Af + grow * DIM + k4);
            else { a[0] = 0.f; a[1] = 0.f; a[2] = 0.f; a[3] = 0.f; }
            u32x2 o;
            o[0] = f2b2u(a[0], a[1]);
            o[1] = f2b2u(a[2], a[3]);
            *(u32x2*)(lA + row * LDA + k4) = o;
        }
        __syncthreads();

#pragma unroll
        for (int sub = 0; sub < 4; ++sub) {
            int r0 = sub * 16;
            short8 xf[4];
#pragma unroll
            for (int kk = 0; kk < 4; ++kk)
                xf[kk] = *(const short8*)(lA + (r0 + l16) * LDA + kk * 32 + quad * 8);
            f32x4 acc[4];
#pragma unroll
            for (int t = 0; t < 4; ++t)
#pragma unroll
                for (int r = 0; r < 4; ++r) acc[t][r] = 0.f;
#pragma unroll
            for (int kk = 0; kk < 4; ++kk)
#pragma unroll
                for (int t = 0; t < 4; ++t)
                    acc[t] = __builtin_amdgcn_mfma_f32_16x16x32_bf16(Wf[t][kk], xf[kk], acc[t], 0, 0, 0);
#pragma unroll
            for (int t = 0; t < 4; ++t) {
                u32x2 o;
                o[0] = f2b2u(acc[t][0], acc[t][1]);
                o[1] = f2b2u(acc[t][2], acc[t][3]);
                *(u32x2*)(lC + (r0 + l16) * LDC + wave * 64 + t * 16 + quad * 4) = o;
            }
        }
        __syncthreads();

#pragma unroll
        for (int half = 0; half < 2; ++half) {
            short* __restrict__ H = half ? Hr : Hl;
#pragma unroll
            for (int i = 0; i < 4; ++i) {
                int c2 = tid + i * 256;
                int row = c2 >> 4;
                int f8 = (c2 & 15) << 3;
                long grow = base + row;
                if (grow < N_NODES) {
                    short8 v = *(const short8*)(lC + row * LDC + half * 128 + f8);
                    *(short8*)(H + grow * DIM + f8) = v;
                }
            }
        }
    }
}

// ---------------- agg1 v3: 4 nodes/wave, one 16-lane group per node ----------------
// Group g streams node's edges serially (1-deep prefetch, full 256B row per load);
// epilogue (x1 relu + 4 projection dots + 16-lane reduce) amortized across 4 groups.
__global__ void agg1_k(const short* __restrict__ Hl, const short* __restrict__ Hr,
                       const int* __restrict__ rowptr, const int* __restrict__ adj,
                       const float* __restrict__ b1,
                       const float* __restrict__ up, const float* __restrict__ uq,
                       const float* __restrict__ vp, const float* __restrict__ vq,
                       float2* __restrict__ S, float2* __restrict__ T) {
    int lane  = threadIdx.x & 63;
    int wavei = blockIdx.x * 4 + (threadIdx.x >> 6);
    int g   = lane >> 4;
    int l16 = lane & 15;
    int f0  = l16 << 3;
    int node = wavei * 4 + g;                    // grid covers exactly N_NODES/4 waves

    int beg = rowptr[node];
    int deg = rowptr[node + 1] - beg;

    // preload up to 16 adjacency entries for this group (coalesced within group)
    int av = (l16 < deg) ? adj[beg + l16] : 0;
    int degc = deg < 16 ? deg : 16;

    f32x2 sum[4];
#pragma unroll
    for (int d = 0; d < 4; ++d) { sum[d][0] = 0.f; sum[d][1] = 0.f; }

    // serial stream with 1-deep prefetch
    u32x4 h0;
    bool v0 = (degc > 0);
    if (v0) {
        int idx = __shfl(av, (g << 4), 64);
        h0 = *(const u32x4*)(Hl + (long)idx * DIM + f0);
    }
    for (int j = 1; j < degc; ++j) {
        int idx = __shfl(av, (g << 4) + j, 64);
        u32x4 h1 = *(const u32x4*)(Hl + (long)idx * DIM + f0);
#pragma unroll
        for (int d = 0; d < 4; ++d) sum[d] += b2f2(h0[d]);
        h0 = h1;
    }
    if (v0) {
#pragma unroll
        for (int d = 0; d < 4; ++d) sum[d] += b2f2(h0[d]);
    }
    // rare fallback: degree > 16
    for (int e = beg + 16; e < beg + deg; ++e) {
        int idx = adj[e];
        u32x4 h = *(const u32x4*)(Hl + (long)idx * DIM + f0);
#pragma unroll
        for (int d = 0; d < 4; ++d) sum[d] += b2f2(h[d]);
    }

    float inv = deg > 0 ? 1.f / (float)deg : 0.f;

    // epilogue: x1 = relu(mean + Hr + b1); projections
    u32x4 hru = *(const u32x4*)(Hr + (long)node * DIM + f0);
    f32x2 x2[4];
#pragma unroll
    for (int d = 0; d < 4; ++d) {
        f32x2 hr2 = b2f2(hru[d]);
        f32x2 bb  = *(const f32x2*)(b1 + f0 + 2 * d);
        f32x2 v   = sum[d] * inv + hr2 + bb;
        x2[d][0] = fmaxf(v[0], 0.f);
        x2[d][1] = fmaxf(v[1], 0.f);
    }

    f32x2 ap2 = {0.f, 0.f}, aq2 = {0.f, 0.f}, tp2 = {0.f, 0.f}, tq2 = {0.f, 0.f};
#pragma unroll
    for (int d = 0; d < 4; ++d) {
        f32x2 u0 = *(const f32x2*)(up + f0 + 2 * d);
        f32x2 u1 = *(const f32x2*)(uq + f0 + 2 * d);
        f32x2 w0 = *(const f32x2*)(vp + f0 + 2 * d);
        f32x2 w1 = *(const f32x2*)(vq + f0 + 2 * d);
        ap2 += x2[d] * u0;
        aq2 += x2[d] * u1;
        tp2 += x2[d] * w0;
        tq2 += x2[d] * w1;
    }
    float ap = ap2[0] + ap2[1], aq = aq2[0] + aq2[1];
    float tp = tp2[0] + tp2[1], tq = tq2[0] + tq2[1];
#pragma unroll
    for (int m = 1; m <= 8; m <<= 1) {           // reduce within 16-lane group
        ap += __shfl_xor(ap, m, 64);
        aq += __shfl_xor(aq, m, 64);
        tp += __shfl_xor(tp, m, 64);
        tq += __shfl_xor(tq, m, 64);
    }
    if (l16 == 0) {
        S[node] = make_float2(ap, aq);
        T[node] = make_float2(tp, tq);
    }
}

// layer-2: p[n] = mean_nbrs(S.x) + T.x + c.x (8B gather per edge)
__global__ void agg2_k(const int* __restrict__ rowptr, const int* __restrict__ adj,
                       const float2* __restrict__ S, const float2* __restrict__ T,
                       const float2* __restrict__ cpq,
                       float* __restrict__ p, float* __restrict__ q) {
    int lane = threadIdx.x & 63;
    int wavei = blockIdx.x * 4 + (threadIdx.x >> 6);
    int slot = lane & 3;
    int node = wavei * 16 + (lane >> 2);
    if (node >= N_NODES) return;
    int beg = rowptr[node], end = rowptr[node + 1];
    float sp = 0.f, sq = 0.f;
    for (int e = beg + slot; e < end; e += 4) {
        float2 v = S[adj[e]];
        sp += v.x; sq += v.y;
    }
    sp += __shfl_xor(sp, 1, 64); sp += __shfl_xor(sp, 2, 64);
    sq += __shfl_xor(sq, 1, 64); sq += __shfl_xor(sq, 2, 64);
    if (slot == 0) {
        int deg = end - beg;
        float inv = deg > 0 ? 1.f / (float)deg : 0.f;
        float2 t = T[node];
        float2 c = *cpq;
        p[node] = sp * inv + t.x + c.x;
        q[node] = sq * inv + t.y + c.y;
    }
}

__global__ void out_k(const int* __restrict__ eli, const float* __restrict__ p,
                      const float* __restrict__ q, const float* __restrict__ blin,
                      float* __restrict__ out) {
    int i = blockIdx.x * blockDim.x + threadIdx.x;
    if (i < N_LABELS) out[i] = p[eli[i]] + q[eli[N_LABELS + i]] + blin[0];
}

// ---------------- launch ----------------

extern "C" void kernel_launch(void* const* d_in, const int* in_sizes, int n_in,
                              void* d_out, int out_size, void* d_ws, size_t ws_size,
                              hipStream_t stream) {
    const int*   edge_index = (const int*)d_in[0];
    const int*   eli        = (const int*)d_in[1];
    const float* emb        = (const float*)d_in[2];
    const float* W1l        = (const float*)d_in[3];
    const float* b1         = (const float*)d_in[4];
    const float* W1r        = (const float*)d_in[5];
    const float* W2l        = (const float*)d_in[6];
    const float* b2         = (const float*)d_in[7];
    const float* W2r        = (const float*)d_in[8];
    const float* Wlin       = (const float*)d_in[9];
    const float* blin       = (const float*)d_in[10];
    float* out = (float*)d_out;

    char* ws = (char*)d_ws;
    size_t off = 0;
    auto alloc = [&](size_t bytes) -> void* {
        off = (off + 255) & ~(size_t)255;
        void* ptr = ws + off;
        off += bytes;
        return ptr;
    };

    short* Hl  = (short*)alloc((size_t)N_NODES * DIM * 2);
    short* Hr  = (short*)alloc((size_t)N_NODES * DIM * 2);
    short* BT1 = (short*)alloc(256 * 128 * 2);
    float* up = (float*)alloc(128 * 4);
    float* uq = (float*)alloc(128 * 4);
    float* vp = (float*)alloc(128 * 4);
    float* vq = (float*)alloc(128 * 4);
    float2* cpq = (float2*)alloc(8);
    int* cnt      = (int*)alloc((size_t)N_NODES * 4);
    int* rowptr   = (int*)alloc((size_t)(N_NODES + 1) * 4);
    int* rank     = (int*)alloc((size_t)N_EDGES * 4);
    int* adj      = (int*)alloc((size_t)N_EDGES * 4);
    int* partials = (int*)alloc(NPARTS * 4);
    float2* S     = (float2*)alloc((size_t)N_NODES * 8);
    float2* T     = (float2*)alloc((size_t)N_NODES * 8);
    float* p      = (float*)alloc((size_t)N_NODES * 4);
    float* q      = (float*)alloc((size_t)N_NODES * 4);

    // zero cnt via DMA, then prep-weights || count+rank in one dispatch
    hipMemsetAsync(cnt, 0, (size_t)N_NODES * 4, stream);
    prep_k<<<130 + CNT_BLOCKS, 256, 0, stream>>>(W1l, W1r, BT1, W2l, W2r, Wlin, b2,
                                                 up, uq, vp, vq, cpq,
                                                 edge_index, cnt, rank);
    scan1_k<<<NPARTS, 256, 0, stream>>>(cnt, rowptr, partials);
    scanB_k<<<NPARTS, 512, 0, stream>>>(partials, rowptr);

    // adjacency fill (atomic-free slice per block) + LDS-staged layer-1 GEMM
    fillgemm_k<<<FG_GRID, 256, 0, stream>>>(edge_index, rank, rowptr, adj, emb, BT1, Hl, Hr);

    // layer-1 aggregation (4 nodes/wave) fused with layer-2 projections
    agg1_k<<<N_NODES / 16, 256, 0, stream>>>(Hl, Hr, rowptr, adj, b1, up, uq, vp, vq, S, T);

    // layer-2 (8B-per-edge gather) + predictor
    agg2_k<<<(N_NODES + 63) / 64, 256, 0, stream>>>(rowptr, adj, S, T, cpq, p, q);
    out_k<<<(N_LABELS + 255) / 256, 256, 0, stream>>>(eli, p, q, blin, out);
}